// Round 10
// baseline (479.611 us; speedup 1.0000x reference)
//
#include <hip/hip_runtime.h>

typedef short v8s __attribute__((ext_vector_type(8)));
typedef unsigned short v8us __attribute__((ext_vector_type(8)));
typedef float v4f __attribute__((ext_vector_type(4)));
typedef float v2f __attribute__((ext_vector_type(2)));
typedef unsigned int uint;
typedef unsigned short ushort_t;

#define N_NODES 100000
#define N_EDGES 1600000
#define NBUCK 782           // ceil(100000/128); bucket = dst>>7
#define NB64 1563           // ceil(100000/64); GEMM grid (64-row tiles)
#define TILE 4096
#define NTILE 391           // ceil(1600000/4096)
#define NB_CONV 12500       // 3.2M 4-elem feature groups / 256
#define NB_W 304            // weight conv/transpose blocks
#define AXLD 136            // LDS x2 row stride (shorts): 272 B = 17 x 16 B

__device__ __forceinline__ unsigned short f2b(float f) {
    uint u = __float_as_uint(f);
    uint r = u + 0x7FFFu + ((u >> 16) & 1u);   // RNE
    return (unsigned short)(r >> 16);
}
// accumulate 2 bf16 (packed in one dword) into a float2 accumulator (v_pk_add_f32 path)
__device__ __forceinline__ void acc2_bf16(v2f& acc, uint d) {
    v2f t;
    t.x = __uint_as_float(d << 16);
    t.y = __uint_as_float(d & 0xFFFF0000u);
    acc += t;
}

// ---------------- prep: weight transpose-convert + feature convert + bucket hist ----------------
// Inputs are f32 (proven: R2 NaN / R3 pass disambiguation).
struct WConvArgs {
    const float* srcW[6];
    ushort_t* dstW[6];
};
__global__ __launch_bounds__(256) void k_prep(WConvArgs a,
                                              const float4* __restrict__ featIn,
                                              ushort_t* __restrict__ featOut,
                                              const int* __restrict__ dst,
                                              int* __restrict__ bcnt) {
    __shared__ int h[NBUCK];
    int b = blockIdx.x, tid = threadIdx.x;
    if (b < NB_W) {
        int j, lb, H;
        if (b < 256)      { j = b >> 6; lb = b & 63; H = 128; }
        else if (b < 276) { j = 4; lb = b - 256; H = 40; }
        else if (b < 280) {
            int idx = (b - 276) * 256 + tid;
            a.dstW[4][(40 + idx / 128) * 128 + (idx & 127)] = 0; return;
        }
        else if (b < 300) { j = 5; lb = b - 280; H = 40; }
        else {
            int idx = (b - 300) * 256 + tid;
            a.dstW[5][(40 + idx / 128) * 128 + (idx & 127)] = 0; return;
        }
        int idx = lb * 256 + tid;
        if (idx >= 128 * H) return;
        int k = idx / H, n = idx % H;
        a.dstW[j][n * 128 + k] = f2b(a.srcW[j][idx]);
        return;
    }
    if (b < NB_W + NB_CONV) {
        int i = (b - NB_W) * 256 + tid;
        float4 v = featIn[i];
        ushort4 o;
        o.x = f2b(v.x); o.y = f2b(v.y); o.z = f2b(v.z); o.w = f2b(v.w);
        ((ushort4*)featOut)[i] = o;
        return;
    }
    int t = b - NB_W - NB_CONV;
    for (int i = tid; i < NBUCK; i += 256) h[i] = 0;
    __syncthreads();
    int t0 = t * TILE;
    int t1 = t0 + TILE; if (t1 > N_EDGES) t1 = N_EDGES;
    for (int i = t0 + tid; i < t1; i += 256) atomicAdd(&h[dst[i] >> 7], 1);
    __syncthreads();
    for (int i = tid; i < NBUCK; i += 256)
        if (h[i]) atomicAdd(&bcnt[i], h[i]);
}

// ---------------- bucket scan ----------------
__global__ __launch_bounds__(1024) void k_bscan(const int* __restrict__ bcnt,
                                                int* __restrict__ boff,
                                                int* __restrict__ bcur) {
    __shared__ int sd[1024];
    int tid = threadIdx.x;
    int v = (tid < NBUCK) ? bcnt[tid] : 0;
    sd[tid] = v; __syncthreads();
    int val = v;
    for (int off = 1; off < 1024; off <<= 1) {
        int t = (tid >= off) ? sd[tid - off] : 0;
        __syncthreads();
        val += t; sd[tid] = val;
        __syncthreads();
    }
    if (tid < NBUCK) {
        int excl = val - v;
        boff[tid] = excl;
        bcur[tid] = excl;
    }
}

// ---------------- tile-local binning -> packed (dstLocal7 | src17) ----------------
__global__ __launch_bounds__(256) void k_bscatter(const int* __restrict__ src,
                                                  const int* __restrict__ dst,
                                                  int* __restrict__ bcur,
                                                  uint* __restrict__ packed) {
    __shared__ int h[NBUCK];
    __shared__ int base[NBUCK];
    int tid = threadIdx.x;
    for (int i = tid; i < NBUCK; i += 256) h[i] = 0;
    __syncthreads();
    int t0 = blockIdx.x * TILE;
    int t1 = t0 + TILE; if (t1 > N_EDGES) t1 = N_EDGES;
    for (int i = t0 + tid; i < t1; i += 256) atomicAdd(&h[dst[i] >> 7], 1);
    __syncthreads();
    for (int i = tid; i < NBUCK; i += 256) {
        int c = h[i];
        base[i] = c ? atomicAdd(&bcur[i], c) : 0;
        h[i] = 0;
    }
    __syncthreads();
    for (int i = t0 + tid; i < t1; i += 256) {
        int d = dst[i];
        int b = d >> 7;
        int r = atomicAdd(&h[b], 1);
        packed[base[b] + r] = ((uint)(d & 127) << 17) | (uint)src[i];
    }
}

// ---------------- one block per bucket: counting sort -> es, rs, inv_deg ----------------
__global__ __launch_bounds__(256) void k_binsort(const uint* __restrict__ packed,
                                                 const int* __restrict__ bcnt,
                                                 const int* __restrict__ boff,
                                                 int* __restrict__ rs,
                                                 float* __restrict__ inv_deg,
                                                 int* __restrict__ es) {
    __shared__ int hist[128], start[128], cur[128];
    int tid = threadIdx.x;
    int b = blockIdx.x;
    int nb = bcnt[b], off = boff[b];
    if (tid < 128) hist[tid] = 0;
    __syncthreads();
    for (int i = tid; i < nb; i += 256) atomicAdd(&hist[packed[off + i] >> 17], 1);
    __syncthreads();
    if (tid < 128) start[tid] = hist[tid];
    __syncthreads();
    for (int o = 1; o < 128; o <<= 1) {
        int v = (tid < 128 && tid >= o) ? start[tid - o] : 0;
        __syncthreads();
        if (tid < 128) start[tid] += v;
        __syncthreads();
    }
    if (tid < 128) {
        int excl = start[tid] - hist[tid];
        int node = b * 128 + tid;
        if (node < N_NODES) {
            rs[node] = off + excl;
            int d = hist[tid];
            inv_deg[node] = 1.0f / (float)(d > 1 ? d : 1);
        }
        cur[tid] = excl;
    }
    if (b == NBUCK - 1 && tid == 0) rs[N_NODES] = N_EDGES;
    __syncthreads();
    for (int i = tid; i < nb; i += 256) {
        uint p = packed[off + i];
        int k = p >> 17;
        int pos = atomicAdd(&cur[k], 1);
        es[off + pos] = (int)(p & 0x1FFFFu);
    }
}

// ---------------- Aggregation (H=128): wave/node, 4 slots x 16 cols, unroll x4 ----------
__global__ __launch_bounds__(256) void k_agg(
    const int* __restrict__ rs,
    const int* __restrict__ es,
    const float* __restrict__ inv_deg,
    const ushort_t* __restrict__ x,
    ushort_t* __restrict__ ax,
    int n) {
    int tid = threadIdx.x;
    int wave = tid >> 6, lane = tid & 63;
    int node = blockIdx.x * 4 + wave;
    if (node >= n) return;
    int sub = lane >> 4;
    int cg = lane & 15;

    int s0 = rs[node], s1 = rs[node + 1];
    v2f acc2[4];
    for (int i = 0; i < 4; ++i) acc2[i] = (v2f){0.f, 0.f};

    int e = s0 + sub;
    for (; e + 12 < s1; e += 16) {
        int sA = es[e], sB = es[e + 4], sC = es[e + 8], sD = es[e + 12];
        uint4 dA = *(const uint4*)(x + (size_t)sA * 128 + cg * 8);
        uint4 dB = *(const uint4*)(x + (size_t)sB * 128 + cg * 8);
        uint4 dC = *(const uint4*)(x + (size_t)sC * 128 + cg * 8);
        uint4 dD = *(const uint4*)(x + (size_t)sD * 128 + cg * 8);
        acc2_bf16(acc2[0], dA.x); acc2_bf16(acc2[1], dA.y); acc2_bf16(acc2[2], dA.z); acc2_bf16(acc2[3], dA.w);
        acc2_bf16(acc2[0], dB.x); acc2_bf16(acc2[1], dB.y); acc2_bf16(acc2[2], dB.z); acc2_bf16(acc2[3], dB.w);
        acc2_bf16(acc2[0], dC.x); acc2_bf16(acc2[1], dC.y); acc2_bf16(acc2[2], dC.z); acc2_bf16(acc2[3], dC.w);
        acc2_bf16(acc2[0], dD.x); acc2_bf16(acc2[1], dD.y); acc2_bf16(acc2[2], dD.z); acc2_bf16(acc2[3], dD.w);
    }
    for (; e < s1; e += 4) {
        int sA = es[e];
        uint4 dA = *(const uint4*)(x + (size_t)sA * 128 + cg * 8);
        acc2_bf16(acc2[0], dA.x); acc2_bf16(acc2[1], dA.y); acc2_bf16(acc2[2], dA.z); acc2_bf16(acc2[3], dA.w);
    }
    float acc[8];
    for (int i = 0; i < 4; ++i) { acc[2 * i] = acc2[i].x; acc[2 * i + 1] = acc2[i].y; }
    for (int off = 16; off < 64; off <<= 1)
        for (int i = 0; i < 8; ++i) acc[i] += __shfl_xor(acc[i], off);

    if (sub == 0) {
        float inv = inv_deg[node];
        v8us ov;
        for (int i = 0; i < 8; ++i) ov[i] = f2b(inv * acc[i]);
        *(v8us*)(ax + (size_t)node * 128 + cg * 8) = ov;
    }
}

// ---------------- Layer-1 dual-A GEMM: 64-row tile, wave owns 16 rows, no LDS/barrier ----
__global__ __launch_bounds__(256) void k_gemm2_g(
    const ushort_t* __restrict__ x,
    const ushort_t* __restrict__ ax,
    const ushort_t* __restrict__ Wts,
    const ushort_t* __restrict__ Wtn,
    const float* __restrict__ bias,
    ushort_t* out,
    int n) {
    int tid = threadIdx.x;
    int wave = tid >> 6, lane = tid & 63;
    int quad = lane >> 4, l16 = lane & 15;
    int rowBase = blockIdx.x * 64 + wave * 16;

    int row = rowBase + l16;
    if (row >= n) row = n - 1;
    v8s a1[4], a2[4];
    for (int kk = 0; kk < 4; ++kk) {
        size_t off = (size_t)row * 128 + kk * 32 + quad * 8;
        a1[kk] = *(const v8s*)(x + off);
        a2[kk] = *(const v8s*)(ax + off);
    }

    v4f accS[8], accN[8];
    for (int t = 0; t < 8; ++t) {
        accS[t] = (v4f){0.f, 0.f, 0.f, 0.f};
        accN[t] = (v4f){0.f, 0.f, 0.f, 0.f};
    }
    for (int t = 0; t < 8; ++t)
        for (int kk = 0; kk < 4; ++kk) {
            size_t bo = (size_t)(t * 16 + l16) * 128 + kk * 32 + quad * 8;
            const v8s bs = *(const v8s*)(Wts + bo);
            const v8s bn = *(const v8s*)(Wtn + bo);
            accS[t] = __builtin_amdgcn_mfma_f32_16x16x32_bf16(a1[kk], bs, accS[t], 0, 0, 0);
            accN[t] = __builtin_amdgcn_mfma_f32_16x16x32_bf16(a2[kk], bn, accN[t], 0, 0, 0);
        }

    for (int t = 0; t < 8; ++t) {
        int col = t * 16 + l16;
        float bv = bias[col];
        for (int r = 0; r < 4; ++r) {
            int orow = rowBase + quad * 4 + r;
            if (orow < n) {
                float v = accS[t][r] + accN[t][r] + bv;
                v = fmaxf(v, 0.f);
                out[(size_t)orow * 128 + col] = f2b(v);
            }
        }
    }
}

// ---------------- Layer-2 GEMM fused with layer-3 split GEMM (wave-private LDS, no barrier) ----
// Wave owns rows [rowBase, rowBase+16). Phase 1: x2 = relu(x@Ws2+ax@Wn2+b2) -> own LDS rows.
// Phase 2: y3 = x2@Ws3+b3 (f32), h3 = x2@Wn3 (bf16) from own LDS rows.
__global__ __launch_bounds__(256) void k_gemm2s(
    const ushort_t* __restrict__ x,
    const ushort_t* __restrict__ ax,
    const ushort_t* __restrict__ Wts2,
    const ushort_t* __restrict__ Wtn2,
    const float* __restrict__ b2,
    const ushort_t* __restrict__ Wts3,
    const ushort_t* __restrict__ Wtn3,
    const float* __restrict__ b3,
    float* __restrict__ y3,
    ushort_t* __restrict__ h3,
    int n) {
    __shared__ ushort_t x2s[64 * AXLD];   // 17.4 KB, wave-private 16-row slices
    int tid = threadIdx.x;
    int wave = tid >> 6, lane = tid & 63;
    int quad = lane >> 4, l16 = lane & 15;
    int rowBase = blockIdx.x * 64 + wave * 16;
    int lslice = wave * 16;

    // ---- Phase 1 ----
    {
        int row = rowBase + l16;
        if (row >= n) row = n - 1;
        v8s a1[4], a2[4];
        for (int kk = 0; kk < 4; ++kk) {
            size_t off = (size_t)row * 128 + kk * 32 + quad * 8;
            a1[kk] = *(const v8s*)(x + off);
            a2[kk] = *(const v8s*)(ax + off);
        }
        v4f accS[8], accN[8];
        for (int t = 0; t < 8; ++t) {
            accS[t] = (v4f){0.f, 0.f, 0.f, 0.f};
            accN[t] = (v4f){0.f, 0.f, 0.f, 0.f};
        }
        for (int t = 0; t < 8; ++t)
            for (int kk = 0; kk < 4; ++kk) {
                size_t bo = (size_t)(t * 16 + l16) * 128 + kk * 32 + quad * 8;
                const v8s bs = *(const v8s*)(Wts2 + bo);
                const v8s bn = *(const v8s*)(Wtn2 + bo);
                accS[t] = __builtin_amdgcn_mfma_f32_16x16x32_bf16(a1[kk], bs, accS[t], 0, 0, 0);
                accN[t] = __builtin_amdgcn_mfma_f32_16x16x32_bf16(a2[kk], bn, accN[t], 0, 0, 0);
            }
        for (int t = 0; t < 8; ++t) {
            int col = t * 16 + l16;
            float bv = b2[col];
            for (int r = 0; r < 4; ++r) {
                float v = accS[t][r] + accN[t][r] + bv;
                v = fmaxf(v, 0.f);
                x2s[(lslice + quad * 4 + r) * AXLD + col] = f2b(v);
            }
        }
    }
    // no __syncthreads: each wave consumes only the LDS rows it wrote (lgkmcnt ordering)

    // ---- Phase 2 ----
    {
        constexpr int H = 40;
        v8s a1[4];
        for (int kk = 0; kk < 4; ++kk)
            a1[kk] = *(const v8s*)(&x2s[(lslice + l16) * AXLD + kk * 32 + quad * 8]);
        v4f accS[3], accN[3];
        for (int t = 0; t < 3; ++t) {
            accS[t] = (v4f){0.f, 0.f, 0.f, 0.f};
            accN[t] = (v4f){0.f, 0.f, 0.f, 0.f};
        }
        for (int t = 0; t < 3; ++t)
            for (int kk = 0; kk < 4; ++kk) {
                size_t bo = (size_t)(t * 16 + l16) * 128 + kk * 32 + quad * 8;
                const v8s bs = *(const v8s*)(Wts3 + bo);
                const v8s bn = *(const v8s*)(Wtn3 + bo);
                accS[t] = __builtin_amdgcn_mfma_f32_16x16x32_bf16(a1[kk], bs, accS[t], 0, 0, 0);
                accN[t] = __builtin_amdgcn_mfma_f32_16x16x32_bf16(a1[kk], bn, accN[t], 0, 0, 0);
            }
        for (int t = 0; t < 3; ++t) {
            int col = t * 16 + l16;
            if (col < H) {
                float bv = b3[col];
                for (int r = 0; r < 4; ++r) {
                    int row = rowBase + quad * 4 + r;
                    if (row < n) {
                        size_t o = (size_t)row * H + col;
                        y3[o] = accS[t][r] + bv;
                        h3[o] = f2b(accN[t][r]);
                    }
                }
            }
        }
    }
}

// ---------------- Layer-3 aggregation (H=40): 8 slots x 8 cols (5 active), f32 out ----------
__global__ __launch_bounds__(256) void k_agg3(
    const int* __restrict__ rs,
    const int* __restrict__ es,
    const float* __restrict__ inv_deg,
    const ushort_t* __restrict__ h3,
    const float* __restrict__ y3,
    float* __restrict__ out,
    int n) {
    int tid = threadIdx.x;
    int wave = tid >> 6, lane = tid & 63;
    int node = blockIdx.x * 4 + wave;
    if (node >= n) return;
    int sub = lane >> 3;
    int cg = lane & 7;
    bool act = (cg < 5);

    int s0 = rs[node], s1 = rs[node + 1];
    v2f acc2[4];
    for (int i = 0; i < 4; ++i) acc2[i] = (v2f){0.f, 0.f};

    if (act) {
        int e = s0 + sub;
        for (; e + 8 < s1; e += 16) {
            int sA = es[e], sB = es[e + 8];
            uint4 dA = *(const uint4*)(h3 + (size_t)sA * 40 + cg * 8);
            uint4 dB = *(const uint4*)(h3 + (size_t)sB * 40 + cg * 8);
            acc2_bf16(acc2[0], dA.x); acc2_bf16(acc2[1], dA.y); acc2_bf16(acc2[2], dA.z); acc2_bf16(acc2[3], dA.w);
            acc2_bf16(acc2[0], dB.x); acc2_bf16(acc2[1], dB.y); acc2_bf16(acc2[2], dB.z); acc2_bf16(acc2[3], dB.w);
        }
        if (e < s1) {
            int sA = es[e];
            uint4 dA = *(const uint4*)(h3 + (size_t)sA * 40 + cg * 8);
            acc2_bf16(acc2[0], dA.x); acc2_bf16(acc2[1], dA.y); acc2_bf16(acc2[2], dA.z); acc2_bf16(acc2[3], dA.w);
        }
    }
    float acc[8];
    for (int i = 0; i < 4; ++i) { acc[2 * i] = acc2[i].x; acc[2 * i + 1] = acc2[i].y; }
    for (int off = 8; off < 64; off <<= 1)
        for (int i = 0; i < 8; ++i) acc[i] += __shfl_xor(acc[i], off);

    if (sub == 0 && act) {
        float inv = inv_deg[node];
        const float4* yp = (const float4*)(y3 + (size_t)node * 40 + cg * 8);
        float4 y0 = yp[0], y1 = yp[1];
        size_t base = (size_t)node * 40 + cg * 8;
        float4* op = (float4*)(out + base);
        op[0] = (float4){y0.x + inv * acc[0], y0.y + inv * acc[1],
                         y0.z + inv * acc[2], y0.w + inv * acc[3]};
        op[1] = (float4){y1.x + inv * acc[4], y1.y + inv * acc[5],
                         y1.z + inv * acc[6], y1.w + inv * acc[7]};
    }
}

__global__ void k_zero16(ushort_t* p, int n) {
    int i = blockIdx.x * 256 + threadIdx.x;
    if (i < n) p[i] = 0;
}

// ---------------- launch ----------------

extern "C" void kernel_launch(void* const* d_in, const int* in_sizes, int n_in,
                              void* d_out, int out_size, void* d_ws, size_t ws_size,
                              hipStream_t stream) {
    const int* src = (const int*)d_in[1];
    const int* dst = (const int*)d_in[2];

    const int N = N_NODES, E = N_EDGES;

    char* ws = (char*)d_ws;
    size_t o = 0;
    auto alloc = [&](size_t bytes) {
        char* p = ws + o;
        o = (o + bytes + 511) & ~(size_t)511;
        return p;
    };
    float* inv_deg = (float*)alloc(N * 4);
    int* rs        = (int*)alloc((N + 1) * 4);
    int* bcnt      = (int*)alloc(NBUCK * 4);
    int* boff      = (int*)alloc(NBUCK * 4);
    int* bcur      = (int*)alloc(NBUCK * 4);
    int* es        = (int*)alloc((size_t)E * 4);
    ushort_t* xbuf = (ushort_t*)alloc((size_t)N * 128 * 2);
    char* aggX_raw = (char*)alloc((size_t)N * 128 * 2);   // 25.6 MB: packed, then aggX
    ushort_t* aggX = (ushort_t*)aggX_raw;
    uint* packed   = (uint*)aggX_raw;                      // pre-CSR only
    char* conv_raw = (char*)alloc((size_t)N * 128 * 2);   // 25.6 MB: conv0, then h3+y3
    ushort_t* conv0 = (ushort_t*)conv_raw;
    ushort_t* h3   = (ushort_t*)conv_raw;                  // 8 MB (layer 3)
    float* y3      = (float*)(conv_raw + (size_t)N * 40 * 2 + 512);  // 16 MB after h3
    ushort_t* Wt[6];
    Wt[0] = (ushort_t*)alloc(128 * 128 * 2);
    Wt[1] = (ushort_t*)alloc(128 * 128 * 2);
    Wt[2] = (ushort_t*)alloc(128 * 128 * 2);
    Wt[3] = (ushort_t*)alloc(128 * 128 * 2);
    Wt[4] = (ushort_t*)alloc(48 * 128 * 2);
    Wt[5] = (ushort_t*)alloc(48 * 128 * 2);
    size_t need = o;

    if (ws_size < need) {
        k_zero16<<<(out_size + 255) / 256, 256, 0, stream>>>((ushort_t*)d_out, out_size);
        return;
    }

    int nb_agg = (N + 3) / 4;        // 25000

    const float* b1 = (const float*)d_in[5];
    const float* b2 = (const float*)d_in[8];
    const float* b3 = (const float*)d_in[11];

    // prep: zero bcnt, then weights+feat+hist in one kernel
    hipMemsetAsync(bcnt, 0, NBUCK * 4, stream);
    WConvArgs wa;
    wa.srcW[0] = (const float*)d_in[3]; wa.srcW[1] = (const float*)d_in[4];
    wa.srcW[2] = (const float*)d_in[6]; wa.srcW[3] = (const float*)d_in[7];
    wa.srcW[4] = (const float*)d_in[9]; wa.srcW[5] = (const float*)d_in[10];
    for (int i = 0; i < 6; ++i) wa.dstW[i] = Wt[i];
    k_prep<<<NB_W + NB_CONV + NTILE, 256, 0, stream>>>(wa, (const float4*)d_in[0], conv0, dst, bcnt);

    // CSR via bucket sort
    k_bscan<<<1, 1024, 0, stream>>>(bcnt, boff, bcur);
    k_bscatter<<<NTILE, 256, 0, stream>>>(src, dst, bcur, packed);
    k_binsort<<<NBUCK, 256, 0, stream>>>(packed, bcnt, boff, rs, inv_deg, es);

    // Layer 1: aggregate conv0 -> aggX; GEMM -> xbuf
    k_agg<<<nb_agg, 256, 0, stream>>>(rs, es, inv_deg, conv0, aggX, N);
    k_gemm2_g<<<NB64, 256, 0, stream>>>(conv0, aggX, Wt[0], Wt[1], b1, xbuf, N);
    // Layer 2: aggregate xbuf -> aggX; fused layer-2 GEMM + layer-3 split GEMM -> y3,h3
    k_agg<<<nb_agg, 256, 0, stream>>>(rs, es, inv_deg, xbuf, aggX, N);
    k_gemm2s<<<NB64, 256, 0, stream>>>(xbuf, aggX, Wt[2], Wt[3], b2, Wt[4], Wt[5], b3, y3, h3, N);
    // Layer 3 aggregation -> d_out (f32)
    k_agg3<<<nb_agg, 256, 0, stream>>>(rs, es, inv_deg, h3, y3, (float*)d_out, N);
}

// Round 11
// 454.732 us; speedup vs baseline: 1.0547x; 1.0547x over previous
//
#include <hip/hip_runtime.h>

typedef short v8s __attribute__((ext_vector_type(8)));
typedef unsigned short v8us __attribute__((ext_vector_type(8)));
typedef float v4f __attribute__((ext_vector_type(4)));
typedef float v2f __attribute__((ext_vector_type(2)));
typedef unsigned int uint;
typedef unsigned short ushort_t;

#define N_NODES 100000
#define N_EDGES 1600000
#define NBUCK 782           // ceil(100000/128); bucket = dst>>7
#define TILE 4096
#define NTILE 391           // ceil(1600000/4096)
#define NB_CONV 12500       // 3.2M 4-elem feature groups / 256
#define NB_W 304            // weight conv/transpose blocks
#define AXLD 136            // LDS x2 row stride (shorts): 272 B = 17 x 16 B

__device__ __forceinline__ unsigned short f2b(float f) {
    uint u = __float_as_uint(f);
    uint r = u + 0x7FFFu + ((u >> 16) & 1u);   // RNE
    return (unsigned short)(r >> 16);
}
// accumulate 2 bf16 (packed in one dword) into a float2 accumulator (v_pk_add_f32 path)
__device__ __forceinline__ void acc2_bf16(v2f& acc, uint d) {
    v2f t;
    t.x = __uint_as_float(d << 16);
    t.y = __uint_as_float(d & 0xFFFF0000u);
    acc += t;
}

// ---------------- prep: weight transpose-convert + feature convert + bucket hist ----------------
// Inputs are f32 (proven: R2 NaN / R3 pass disambiguation).
struct WConvArgs {
    const float* srcW[6];
    ushort_t* dstW[6];
};
__global__ __launch_bounds__(256) void k_prep(WConvArgs a,
                                              const float4* __restrict__ featIn,
                                              ushort_t* __restrict__ featOut,
                                              const int* __restrict__ dst,
                                              int* __restrict__ bcnt) {
    __shared__ int h[NBUCK];
    int b = blockIdx.x, tid = threadIdx.x;
    if (b < NB_W) {
        int j, lb, H;
        if (b < 256)      { j = b >> 6; lb = b & 63; H = 128; }
        else if (b < 276) { j = 4; lb = b - 256; H = 40; }
        else if (b < 280) {
            int idx = (b - 276) * 256 + tid;
            a.dstW[4][(40 + idx / 128) * 128 + (idx & 127)] = 0; return;
        }
        else if (b < 300) { j = 5; lb = b - 280; H = 40; }
        else {
            int idx = (b - 300) * 256 + tid;
            a.dstW[5][(40 + idx / 128) * 128 + (idx & 127)] = 0; return;
        }
        int idx = lb * 256 + tid;
        if (idx >= 128 * H) return;
        int k = idx / H, n = idx % H;
        a.dstW[j][n * 128 + k] = f2b(a.srcW[j][idx]);
        return;
    }
    if (b < NB_W + NB_CONV) {
        int i = (b - NB_W) * 256 + tid;
        float4 v = featIn[i];
        ushort4 o;
        o.x = f2b(v.x); o.y = f2b(v.y); o.z = f2b(v.z); o.w = f2b(v.w);
        ((ushort4*)featOut)[i] = o;
        return;
    }
    int t = b - NB_W - NB_CONV;
    for (int i = tid; i < NBUCK; i += 256) h[i] = 0;
    __syncthreads();
    int t0 = t * TILE;
    int t1 = t0 + TILE; if (t1 > N_EDGES) t1 = N_EDGES;
    for (int i = t0 + tid; i < t1; i += 256) atomicAdd(&h[dst[i] >> 7], 1);
    __syncthreads();
    for (int i = tid; i < NBUCK; i += 256)
        if (h[i]) atomicAdd(&bcnt[i], h[i]);
}

// ---------------- bucket scan ----------------
__global__ __launch_bounds__(1024) void k_bscan(const int* __restrict__ bcnt,
                                                int* __restrict__ boff,
                                                int* __restrict__ bcur) {
    __shared__ int sd[1024];
    int tid = threadIdx.x;
    int v = (tid < NBUCK) ? bcnt[tid] : 0;
    sd[tid] = v; __syncthreads();
    int val = v;
    for (int off = 1; off < 1024; off <<= 1) {
        int t = (tid >= off) ? sd[tid - off] : 0;
        __syncthreads();
        val += t; sd[tid] = val;
        __syncthreads();
    }
    if (tid < NBUCK) {
        int excl = val - v;
        boff[tid] = excl;
        bcur[tid] = excl;
    }
}

// ---------------- tile-local binning -> packed (dstLocal7 | src17) ----------------
__global__ __launch_bounds__(256) void k_bscatter(const int* __restrict__ src,
                                                  const int* __restrict__ dst,
                                                  int* __restrict__ bcur,
                                                  uint* __restrict__ packed) {
    __shared__ int h[NBUCK];
    __shared__ int base[NBUCK];
    int tid = threadIdx.x;
    for (int i = tid; i < NBUCK; i += 256) h[i] = 0;
    __syncthreads();
    int t0 = blockIdx.x * TILE;
    int t1 = t0 + TILE; if (t1 > N_EDGES) t1 = N_EDGES;
    for (int i = t0 + tid; i < t1; i += 256) atomicAdd(&h[dst[i] >> 7], 1);
    __syncthreads();
    for (int i = tid; i < NBUCK; i += 256) {
        int c = h[i];
        base[i] = c ? atomicAdd(&bcur[i], c) : 0;
        h[i] = 0;
    }
    __syncthreads();
    for (int i = t0 + tid; i < t1; i += 256) {
        int d = dst[i];
        int b = d >> 7;
        int r = atomicAdd(&h[b], 1);
        packed[base[b] + r] = ((uint)(d & 127) << 17) | (uint)src[i];
    }
}

// ---------------- one block per bucket: counting sort -> es, rs, inv_deg ----------------
__global__ __launch_bounds__(256) void k_binsort(const uint* __restrict__ packed,
                                                 const int* __restrict__ bcnt,
                                                 const int* __restrict__ boff,
                                                 int* __restrict__ rs,
                                                 float* __restrict__ inv_deg,
                                                 int* __restrict__ es) {
    __shared__ int hist[128], start[128], cur[128];
    int tid = threadIdx.x;
    int b = blockIdx.x;
    int nb = bcnt[b], off = boff[b];
    if (tid < 128) hist[tid] = 0;
    __syncthreads();
    for (int i = tid; i < nb; i += 256) atomicAdd(&hist[packed[off + i] >> 17], 1);
    __syncthreads();
    if (tid < 128) start[tid] = hist[tid];
    __syncthreads();
    for (int o = 1; o < 128; o <<= 1) {
        int v = (tid < 128 && tid >= o) ? start[tid - o] : 0;
        __syncthreads();
        if (tid < 128) start[tid] += v;
        __syncthreads();
    }
    if (tid < 128) {
        int excl = start[tid] - hist[tid];
        int node = b * 128 + tid;
        if (node < N_NODES) {
            rs[node] = off + excl;
            int d = hist[tid];
            inv_deg[node] = 1.0f / (float)(d > 1 ? d : 1);
        }
        cur[tid] = excl;
    }
    if (b == NBUCK - 1 && tid == 0) rs[N_NODES] = N_EDGES;
    __syncthreads();
    for (int i = tid; i < nb; i += 256) {
        uint p = packed[off + i];
        int k = p >> 17;
        int pos = atomicAdd(&cur[k], 1);
        es[off + pos] = (int)(p & 0x1FFFFu);
    }
}

// ---------------- Aggregation (H=128): wave/node, 4 slots x 16 cols, unroll x4 ----------
__global__ __launch_bounds__(256) void k_agg(
    const int* __restrict__ rs,
    const int* __restrict__ es,
    const float* __restrict__ inv_deg,
    const ushort_t* __restrict__ x,
    ushort_t* __restrict__ ax,
    int n) {
    int tid = threadIdx.x;
    int wave = tid >> 6, lane = tid & 63;
    int node = blockIdx.x * 4 + wave;
    if (node >= n) return;
    int sub = lane >> 4;
    int cg = lane & 15;

    int s0 = rs[node], s1 = rs[node + 1];
    v2f acc2[4];
    for (int i = 0; i < 4; ++i) acc2[i] = (v2f){0.f, 0.f};

    int e = s0 + sub;
    for (; e + 12 < s1; e += 16) {
        int sA = es[e], sB = es[e + 4], sC = es[e + 8], sD = es[e + 12];
        uint4 dA = *(const uint4*)(x + (size_t)sA * 128 + cg * 8);
        uint4 dB = *(const uint4*)(x + (size_t)sB * 128 + cg * 8);
        uint4 dC = *(const uint4*)(x + (size_t)sC * 128 + cg * 8);
        uint4 dD = *(const uint4*)(x + (size_t)sD * 128 + cg * 8);
        acc2_bf16(acc2[0], dA.x); acc2_bf16(acc2[1], dA.y); acc2_bf16(acc2[2], dA.z); acc2_bf16(acc2[3], dA.w);
        acc2_bf16(acc2[0], dB.x); acc2_bf16(acc2[1], dB.y); acc2_bf16(acc2[2], dB.z); acc2_bf16(acc2[3], dB.w);
        acc2_bf16(acc2[0], dC.x); acc2_bf16(acc2[1], dC.y); acc2_bf16(acc2[2], dC.z); acc2_bf16(acc2[3], dC.w);
        acc2_bf16(acc2[0], dD.x); acc2_bf16(acc2[1], dD.y); acc2_bf16(acc2[2], dD.z); acc2_bf16(acc2[3], dD.w);
    }
    for (; e < s1; e += 4) {
        int sA = es[e];
        uint4 dA = *(const uint4*)(x + (size_t)sA * 128 + cg * 8);
        acc2_bf16(acc2[0], dA.x); acc2_bf16(acc2[1], dA.y); acc2_bf16(acc2[2], dA.z); acc2_bf16(acc2[3], dA.w);
    }
    float acc[8];
    for (int i = 0; i < 4; ++i) { acc[2 * i] = acc2[i].x; acc[2 * i + 1] = acc2[i].y; }
    for (int off = 16; off < 64; off <<= 1)
        for (int i = 0; i < 8; ++i) acc[i] += __shfl_xor(acc[i], off);

    if (sub == 0) {
        float inv = inv_deg[node];
        v8us ov;
        for (int i = 0; i < 8; ++i) ov[i] = f2b(inv * acc[i]);
        *(v8us*)(ax + (size_t)node * 128 + cg * 8) = ov;
    }
}

// ---------------- Layer-1 dual-A GEMM: 128-row tile, single accumulator, barrier-free ----
__global__ __launch_bounds__(256) void k_gemm2_g(
    const ushort_t* __restrict__ x,
    const ushort_t* __restrict__ ax,
    const ushort_t* __restrict__ Wts,
    const ushort_t* __restrict__ Wtn,
    const float* __restrict__ bias,
    ushort_t* out,
    int n) {
    int tid = threadIdx.x;
    int wave = tid >> 6, lane = tid & 63;
    int quad = lane >> 4, l16 = lane & 15;
    int rowBase = blockIdx.x * 128 + wave * 32;

    v4f acc[2][8];
    for (int rt = 0; rt < 2; ++rt)
        for (int t = 0; t < 8; ++t)
            acc[rt][t] = (v4f){0.f, 0.f, 0.f, 0.f};

    for (int kk = 0; kk < 4; ++kk) {
        v8s a1[2], a2[2];
        for (int rt = 0; rt < 2; ++rt) {
            int row = rowBase + rt * 16 + l16;
            if (row >= n) row = n - 1;
            size_t off = (size_t)row * 128 + kk * 32 + quad * 8;
            a1[rt] = *(const v8s*)(x + off);
            a2[rt] = *(const v8s*)(ax + off);
        }
        for (int t = 0; t < 8; ++t) {
            size_t bo = (size_t)(t * 16 + l16) * 128 + kk * 32 + quad * 8;
            const v8s bs = *(const v8s*)(Wts + bo);
            const v8s bn = *(const v8s*)(Wtn + bo);
            for (int rt = 0; rt < 2; ++rt) {
                acc[rt][t] = __builtin_amdgcn_mfma_f32_16x16x32_bf16(a1[rt], bs, acc[rt][t], 0, 0, 0);
                acc[rt][t] = __builtin_amdgcn_mfma_f32_16x16x32_bf16(a2[rt], bn, acc[rt][t], 0, 0, 0);
            }
        }
    }

    for (int rt = 0; rt < 2; ++rt)
        for (int t = 0; t < 8; ++t) {
            int col = t * 16 + l16;
            float bv = bias[col];
            for (int r = 0; r < 4; ++r) {
                int row = rowBase + rt * 16 + quad * 4 + r;
                if (row < n) {
                    float v = acc[rt][t][r] + bv;
                    v = fmaxf(v, 0.f);
                    out[(size_t)row * 128 + col] = f2b(v);
                }
            }
        }
}

// ---------------- Layer-2 GEMM fused with layer-3 split GEMM (wave-private LDS) ----------
// Phase 1: x2 = relu(x@Ws2 + ax@Wn2 + b2) -> LDS (single acc). No barrier: wave-private rows.
// Phase 2: y3 = x2@Ws3 + b3 (f32), h3 = x2@Wn3 (bf16).
__global__ __launch_bounds__(256) void k_gemm2s(
    const ushort_t* __restrict__ x,
    const ushort_t* __restrict__ ax,
    const ushort_t* __restrict__ Wts2,
    const ushort_t* __restrict__ Wtn2,
    const float* __restrict__ b2,
    const ushort_t* __restrict__ Wts3,
    const ushort_t* __restrict__ Wtn3,
    const float* __restrict__ b3,
    float* __restrict__ y3,
    ushort_t* __restrict__ h3,
    int n) {
    __shared__ ushort_t x2s[128 * AXLD];   // 34.8 KB, wave-private 32-row slices
    int tid = threadIdx.x;
    int wave = tid >> 6, lane = tid & 63;
    int quad = lane >> 4, l16 = lane & 15;
    int b = blockIdx.x;

    // ---- Phase 1 ----
    {
        int rowBase = b * 128 + wave * 32;
        v4f acc[2][8];
        for (int rt = 0; rt < 2; ++rt)
            for (int t = 0; t < 8; ++t)
                acc[rt][t] = (v4f){0.f, 0.f, 0.f, 0.f};
        for (int kk = 0; kk < 4; ++kk) {
            v8s a1[2], a2[2];
            for (int rt = 0; rt < 2; ++rt) {
                int row = rowBase + rt * 16 + l16;
                if (row >= n) row = n - 1;
                size_t off = (size_t)row * 128 + kk * 32 + quad * 8;
                a1[rt] = *(const v8s*)(x + off);
                a2[rt] = *(const v8s*)(ax + off);
            }
            for (int t = 0; t < 8; ++t) {
                size_t bo = (size_t)(t * 16 + l16) * 128 + kk * 32 + quad * 8;
                const v8s bs = *(const v8s*)(Wts2 + bo);
                const v8s bn = *(const v8s*)(Wtn2 + bo);
                for (int rt = 0; rt < 2; ++rt) {
                    acc[rt][t] = __builtin_amdgcn_mfma_f32_16x16x32_bf16(a1[rt], bs, acc[rt][t], 0, 0, 0);
                    acc[rt][t] = __builtin_amdgcn_mfma_f32_16x16x32_bf16(a2[rt], bn, acc[rt][t], 0, 0, 0);
                }
            }
        }
        for (int rt = 0; rt < 2; ++rt)
            for (int t = 0; t < 8; ++t) {
                int col = t * 16 + l16;
                float bv = b2[col];
                for (int r = 0; r < 4; ++r) {
                    int rowL = wave * 32 + rt * 16 + quad * 4 + r;
                    float v = acc[rt][t][r] + bv;
                    v = fmaxf(v, 0.f);
                    x2s[rowL * AXLD + col] = f2b(v);
                }
            }
    }
    // no __syncthreads: each wave consumes only the LDS rows it wrote (lgkmcnt ordering)

    // ---- Phase 2 ----
    {
        constexpr int H = 40;
        int rowBaseL = wave * 32;
        v4f accS[2][3], accN[2][3];
        for (int rt = 0; rt < 2; ++rt)
            for (int t = 0; t < 3; ++t) {
                accS[rt][t] = (v4f){0.f, 0.f, 0.f, 0.f};
                accN[rt][t] = (v4f){0.f, 0.f, 0.f, 0.f};
            }
        for (int kk = 0; kk < 4; ++kk) {
            v8s a1[2];
            for (int rt = 0; rt < 2; ++rt)
                a1[rt] = *(const v8s*)(&x2s[(rowBaseL + rt * 16 + l16) * AXLD + kk * 32 + quad * 8]);
            for (int t = 0; t < 3; ++t) {
                size_t bo = (size_t)(t * 16 + l16) * 128 + kk * 32 + quad * 8;
                const v8s bs = *(const v8s*)(Wts3 + bo);
                const v8s bn = *(const v8s*)(Wtn3 + bo);
                for (int rt = 0; rt < 2; ++rt) {
                    accS[rt][t] = __builtin_amdgcn_mfma_f32_16x16x32_bf16(a1[rt], bs, accS[rt][t], 0, 0, 0);
                    accN[rt][t] = __builtin_amdgcn_mfma_f32_16x16x32_bf16(a1[rt], bn, accN[rt][t], 0, 0, 0);
                }
            }
        }
        for (int rt = 0; rt < 2; ++rt)
            for (int t = 0; t < 3; ++t) {
                int col = t * 16 + l16;
                if (col < H) {
                    float bv = b3[col];
                    for (int r = 0; r < 4; ++r) {
                        int row = b * 128 + rowBaseL + rt * 16 + quad * 4 + r;
                        if (row < n) {
                            size_t o = (size_t)row * H + col;
                            y3[o] = accS[rt][t][r] + bv;
                            h3[o] = f2b(accN[rt][t][r]);
                        }
                    }
                }
            }
    }
}

// ---------------- Layer-3 aggregation (H=40): 8 slots x 8 cols (5 active), f32 out ----------
__global__ __launch_bounds__(256) void k_agg3(
    const int* __restrict__ rs,
    const int* __restrict__ es,
    const float* __restrict__ inv_deg,
    const ushort_t* __restrict__ h3,
    const float* __restrict__ y3,
    float* __restrict__ out,
    int n) {
    int tid = threadIdx.x;
    int wave = tid >> 6, lane = tid & 63;
    int node = blockIdx.x * 4 + wave;
    if (node >= n) return;
    int sub = lane >> 3;
    int cg = lane & 7;
    bool act = (cg < 5);

    int s0 = rs[node], s1 = rs[node + 1];
    v2f acc2[4];
    for (int i = 0; i < 4; ++i) acc2[i] = (v2f){0.f, 0.f};

    if (act) {
        int e = s0 + sub;
        for (; e + 8 < s1; e += 16) {
            int sA = es[e], sB = es[e + 8];
            uint4 dA = *(const uint4*)(h3 + (size_t)sA * 40 + cg * 8);
            uint4 dB = *(const uint4*)(h3 + (size_t)sB * 40 + cg * 8);
            acc2_bf16(acc2[0], dA.x); acc2_bf16(acc2[1], dA.y); acc2_bf16(acc2[2], dA.z); acc2_bf16(acc2[3], dA.w);
            acc2_bf16(acc2[0], dB.x); acc2_bf16(acc2[1], dB.y); acc2_bf16(acc2[2], dB.z); acc2_bf16(acc2[3], dB.w);
        }
        if (e < s1) {
            int sA = es[e];
            uint4 dA = *(const uint4*)(h3 + (size_t)sA * 40 + cg * 8);
            acc2_bf16(acc2[0], dA.x); acc2_bf16(acc2[1], dA.y); acc2_bf16(acc2[2], dA.z); acc2_bf16(acc2[3], dA.w);
        }
    }
    float acc[8];
    for (int i = 0; i < 4; ++i) { acc[2 * i] = acc2[i].x; acc[2 * i + 1] = acc2[i].y; }
    for (int off = 8; off < 64; off <<= 1)
        for (int i = 0; i < 8; ++i) acc[i] += __shfl_xor(acc[i], off);

    if (sub == 0 && act) {
        float inv = inv_deg[node];
        const float4* yp = (const float4*)(y3 + (size_t)node * 40 + cg * 8);
        float4 y0 = yp[0], y1 = yp[1];
        size_t base = (size_t)node * 40 + cg * 8;
        float4* op = (float4*)(out + base);
        op[0] = (float4){y0.x + inv * acc[0], y0.y + inv * acc[1],
                         y0.z + inv * acc[2], y0.w + inv * acc[3]};
        op[1] = (float4){y1.x + inv * acc[4], y1.y + inv * acc[5],
                         y1.z + inv * acc[6], y1.w + inv * acc[7]};
    }
}

__global__ void k_zero16(ushort_t* p, int n) {
    int i = blockIdx.x * 256 + threadIdx.x;
    if (i < n) p[i] = 0;
}

// ---------------- launch ----------------

extern "C" void kernel_launch(void* const* d_in, const int* in_sizes, int n_in,
                              void* d_out, int out_size, void* d_ws, size_t ws_size,
                              hipStream_t stream) {
    const int* src = (const int*)d_in[1];
    const int* dst = (const int*)d_in[2];

    const int N = N_NODES, E = N_EDGES;

    char* ws = (char*)d_ws;
    size_t o = 0;
    auto alloc = [&](size_t bytes) {
        char* p = ws + o;
        o = (o + bytes + 511) & ~(size_t)511;
        return p;
    };
    float* inv_deg = (float*)alloc(N * 4);
    int* rs        = (int*)alloc((N + 1) * 4);
    int* bcnt      = (int*)alloc(NBUCK * 4);
    int* boff      = (int*)alloc(NBUCK * 4);
    int* bcur      = (int*)alloc(NBUCK * 4);
    int* es        = (int*)alloc((size_t)E * 4);
    ushort_t* xbuf = (ushort_t*)alloc((size_t)N * 128 * 2);
    char* aggX_raw = (char*)alloc((size_t)N * 128 * 2);   // 25.6 MB: packed, then aggX
    ushort_t* aggX = (ushort_t*)aggX_raw;
    uint* packed   = (uint*)aggX_raw;                      // pre-CSR only
    char* conv_raw = (char*)alloc((size_t)N * 128 * 2);   // 25.6 MB: conv0, then h3+y3
    ushort_t* conv0 = (ushort_t*)conv_raw;
    ushort_t* h3   = (ushort_t*)conv_raw;                  // 8 MB (layer 3)
    float* y3      = (float*)(conv_raw + (size_t)N * 40 * 2 + 512);  // 16 MB after h3
    ushort_t* Wt[6];
    Wt[0] = (ushort_t*)alloc(128 * 128 * 2);
    Wt[1] = (ushort_t*)alloc(128 * 128 * 2);
    Wt[2] = (ushort_t*)alloc(128 * 128 * 2);
    Wt[3] = (ushort_t*)alloc(128 * 128 * 2);
    Wt[4] = (ushort_t*)alloc(48 * 128 * 2);
    Wt[5] = (ushort_t*)alloc(48 * 128 * 2);
    size_t need = o;

    if (ws_size < need) {
        k_zero16<<<(out_size + 255) / 256, 256, 0, stream>>>((ushort_t*)d_out, out_size);
        return;
    }

    int nb_agg = (N + 3) / 4;        // 25000

    const float* b1 = (const float*)d_in[5];
    const float* b2 = (const float*)d_in[8];
    const float* b3 = (const float*)d_in[11];

    // prep: zero bcnt, then weights+feat+hist in one kernel
    hipMemsetAsync(bcnt, 0, NBUCK * 4, stream);
    WConvArgs wa;
    wa.srcW[0] = (const float*)d_in[3]; wa.srcW[1] = (const float*)d_in[4];
    wa.srcW[2] = (const float*)d_in[6]; wa.srcW[3] = (const float*)d_in[7];
    wa.srcW[4] = (const float*)d_in[9]; wa.srcW[5] = (const float*)d_in[10];
    for (int i = 0; i < 6; ++i) wa.dstW[i] = Wt[i];
    k_prep<<<NB_W + NB_CONV + NTILE, 256, 0, stream>>>(wa, (const float4*)d_in[0], conv0, dst, bcnt);

    // CSR via bucket sort
    k_bscan<<<1, 1024, 0, stream>>>(bcnt, boff, bcur);
    k_bscatter<<<NTILE, 256, 0, stream>>>(src, dst, bcur, packed);
    k_binsort<<<NBUCK, 256, 0, stream>>>(packed, bcnt, boff, rs, inv_deg, es);

    // Layer 1: aggregate conv0 -> aggX; GEMM -> xbuf
    k_agg<<<nb_agg, 256, 0, stream>>>(rs, es, inv_deg, conv0, aggX, N);
    k_gemm2_g<<<NBUCK, 256, 0, stream>>>(conv0, aggX, Wt[0], Wt[1], b1, xbuf, N);
    // Layer 2: aggregate xbuf -> aggX; fused layer-2 GEMM + layer-3 split GEMM -> y3,h3
    k_agg<<<nb_agg, 256, 0, stream>>>(rs, es, inv_deg, xbuf, aggX, N);
    k_gemm2s<<<NBUCK, 256, 0, stream>>>(xbuf, aggX, Wt[2], Wt[3], b2, Wt[4], Wt[5], b3, y3, h3, N);
    // Layer 3 aggregation -> d_out (f32)
    k_agg3<<<nb_agg, 256, 0, stream>>>(rs, es, inv_deg, h3, y3, (float*)d_out, N);
}

// Round 12
// 418.498 us; speedup vs baseline: 1.1460x; 1.0866x over previous
//
#include <hip/hip_runtime.h>

typedef short v8s __attribute__((ext_vector_type(8)));
typedef unsigned short v8us __attribute__((ext_vector_type(8)));
typedef float v4f __attribute__((ext_vector_type(4)));
typedef float v2f __attribute__((ext_vector_type(2)));
typedef unsigned int uint;
typedef unsigned short ushort_t;

#define N_NODES 100000
#define N_EDGES 1600000
#define NBUCK 782           // ceil(100000/128); bucket = dst>>7
#define TILE 4096
#define NTILE 391           // ceil(1600000/4096)
#define NB_CONV 12500       // 3.2M 4-elem feature groups / 256
#define NB_W 304            // weight conv/transpose blocks
#define AXLD 136            // LDS x2 row stride (shorts): 272 B = 17 x 16 B

__device__ __forceinline__ unsigned short f2b(float f) {
    uint u = __float_as_uint(f);
    uint r = u + 0x7FFFu + ((u >> 16) & 1u);   // RNE
    return (unsigned short)(r >> 16);
}
// accumulate 2 bf16 (packed in one dword) into a float2 accumulator (v_pk_add_f32 path)
__device__ __forceinline__ void acc2_bf16(v2f& acc, uint d) {
    v2f t;
    t.x = __uint_as_float(d << 16);
    t.y = __uint_as_float(d & 0xFFFF0000u);
    acc += t;
}

// ---------------- prep: weight transpose-convert + feature convert + bucket hist ----------------
// Inputs are f32 (proven: R2 NaN / R3 pass disambiguation).
struct WConvArgs {
    const float* srcW[6];
    ushort_t* dstW[6];
};
__global__ __launch_bounds__(256) void k_prep(WConvArgs a,
                                              const float4* __restrict__ featIn,
                                              ushort_t* __restrict__ featOut,
                                              const int* __restrict__ dst,
                                              int* __restrict__ bcnt) {
    __shared__ int h[NBUCK];
    int b = blockIdx.x, tid = threadIdx.x;
    if (b < NB_W) {
        int j, lb, H;
        if (b < 256)      { j = b >> 6; lb = b & 63; H = 128; }
        else if (b < 276) { j = 4; lb = b - 256; H = 40; }
        else if (b < 280) {
            int idx = (b - 276) * 256 + tid;
            a.dstW[4][(40 + idx / 128) * 128 + (idx & 127)] = 0; return;
        }
        else if (b < 300) { j = 5; lb = b - 280; H = 40; }
        else {
            int idx = (b - 300) * 256 + tid;
            a.dstW[5][(40 + idx / 128) * 128 + (idx & 127)] = 0; return;
        }
        int idx = lb * 256 + tid;
        if (idx >= 128 * H) return;
        int k = idx / H, n = idx % H;
        a.dstW[j][n * 128 + k] = f2b(a.srcW[j][idx]);
        return;
    }
    if (b < NB_W + NB_CONV) {
        int i = (b - NB_W) * 256 + tid;
        float4 v = featIn[i];
        ushort4 o;
        o.x = f2b(v.x); o.y = f2b(v.y); o.z = f2b(v.z); o.w = f2b(v.w);
        ((ushort4*)featOut)[i] = o;
        return;
    }
    int t = b - NB_W - NB_CONV;
    for (int i = tid; i < NBUCK; i += 256) h[i] = 0;
    __syncthreads();
    int t0 = t * TILE;
    int t1 = t0 + TILE; if (t1 > N_EDGES) t1 = N_EDGES;
    for (int i = t0 + tid; i < t1; i += 256) atomicAdd(&h[dst[i] >> 7], 1);
    __syncthreads();
    for (int i = tid; i < NBUCK; i += 256)
        if (h[i]) atomicAdd(&bcnt[i], h[i]);
}

// ---------------- bucket scan ----------------
__global__ __launch_bounds__(1024) void k_bscan(const int* __restrict__ bcnt,
                                                int* __restrict__ boff,
                                                int* __restrict__ bcur) {
    __shared__ int sd[1024];
    int tid = threadIdx.x;
    int v = (tid < NBUCK) ? bcnt[tid] : 0;
    sd[tid] = v; __syncthreads();
    int val = v;
    for (int off = 1; off < 1024; off <<= 1) {
        int t = (tid >= off) ? sd[tid - off] : 0;
        __syncthreads();
        val += t; sd[tid] = val;
        __syncthreads();
    }
    if (tid < NBUCK) {
        int excl = val - v;
        boff[tid] = excl;
        bcur[tid] = excl;
    }
}

// ---------------- tile-local binning -> packed (dstLocal7 | src17) ----------------
__global__ __launch_bounds__(256) void k_bscatter(const int* __restrict__ src,
                                                  const int* __restrict__ dst,
                                                  int* __restrict__ bcur,
                                                  uint* __restrict__ packed) {
    __shared__ int h[NBUCK];
    __shared__ int base[NBUCK];
    int tid = threadIdx.x;
    for (int i = tid; i < NBUCK; i += 256) h[i] = 0;
    __syncthreads();
    int t0 = blockIdx.x * TILE;
    int t1 = t0 + TILE; if (t1 > N_EDGES) t1 = N_EDGES;
    for (int i = t0 + tid; i < t1; i += 256) atomicAdd(&h[dst[i] >> 7], 1);
    __syncthreads();
    for (int i = tid; i < NBUCK; i += 256) {
        int c = h[i];
        base[i] = c ? atomicAdd(&bcur[i], c) : 0;
        h[i] = 0;
    }
    __syncthreads();
    for (int i = t0 + tid; i < t1; i += 256) {
        int d = dst[i];
        int b = d >> 7;
        int r = atomicAdd(&h[b], 1);
        packed[base[b] + r] = ((uint)(d & 127) << 17) | (uint)src[i];
    }
}

// ---------------- one block per bucket: counting sort -> es, rs, inv_deg ----------------
__global__ __launch_bounds__(256) void k_binsort(const uint* __restrict__ packed,
                                                 const int* __restrict__ bcnt,
                                                 const int* __restrict__ boff,
                                                 int* __restrict__ rs,
                                                 float* __restrict__ inv_deg,
                                                 int* __restrict__ es) {
    __shared__ int hist[128], start[128], cur[128];
    int tid = threadIdx.x;
    int b = blockIdx.x;
    int nb = bcnt[b], off = boff[b];
    if (tid < 128) hist[tid] = 0;
    __syncthreads();
    for (int i = tid; i < nb; i += 256) atomicAdd(&hist[packed[off + i] >> 17], 1);
    __syncthreads();
    if (tid < 128) start[tid] = hist[tid];
    __syncthreads();
    for (int o = 1; o < 128; o <<= 1) {
        int v = (tid < 128 && tid >= o) ? start[tid - o] : 0;
        __syncthreads();
        if (tid < 128) start[tid] += v;
        __syncthreads();
    }
    if (tid < 128) {
        int excl = start[tid] - hist[tid];
        int node = b * 128 + tid;
        if (node < N_NODES) {
            rs[node] = off + excl;
            int d = hist[tid];
            inv_deg[node] = 1.0f / (float)(d > 1 ? d : 1);
        }
        cur[tid] = excl;
    }
    if (b == NBUCK - 1 && tid == 0) rs[N_NODES] = N_EDGES;
    __syncthreads();
    for (int i = tid; i < nb; i += 256) {
        uint p = packed[off + i];
        int k = p >> 17;
        int pos = atomicAdd(&cur[k], 1);
        es[off + pos] = (int)(p & 0x1FFFFu);
    }
}

// ---------------- Aggregation (H=128): wave/node, 4 slots x 16 cols, unroll x4 ----------
__global__ __launch_bounds__(256) void k_agg(
    const int* __restrict__ rs,
    const int* __restrict__ es,
    const float* __restrict__ inv_deg,
    const ushort_t* __restrict__ x,
    ushort_t* __restrict__ ax,
    int n) {
    int tid = threadIdx.x;
    int wave = tid >> 6, lane = tid & 63;
    int node = blockIdx.x * 4 + wave;
    if (node >= n) return;
    int sub = lane >> 4;
    int cg = lane & 15;

    int s0 = rs[node], s1 = rs[node + 1];
    v2f acc2[4];
    for (int i = 0; i < 4; ++i) acc2[i] = (v2f){0.f, 0.f};

    int e = s0 + sub;
    for (; e + 12 < s1; e += 16) {
        int sA = es[e], sB = es[e + 4], sC = es[e + 8], sD = es[e + 12];
        uint4 dA = *(const uint4*)(x + (size_t)sA * 128 + cg * 8);
        uint4 dB = *(const uint4*)(x + (size_t)sB * 128 + cg * 8);
        uint4 dC = *(const uint4*)(x + (size_t)sC * 128 + cg * 8);
        uint4 dD = *(const uint4*)(x + (size_t)sD * 128 + cg * 8);
        acc2_bf16(acc2[0], dA.x); acc2_bf16(acc2[1], dA.y); acc2_bf16(acc2[2], dA.z); acc2_bf16(acc2[3], dA.w);
        acc2_bf16(acc2[0], dB.x); acc2_bf16(acc2[1], dB.y); acc2_bf16(acc2[2], dB.z); acc2_bf16(acc2[3], dB.w);
        acc2_bf16(acc2[0], dC.x); acc2_bf16(acc2[1], dC.y); acc2_bf16(acc2[2], dC.z); acc2_bf16(acc2[3], dC.w);
        acc2_bf16(acc2[0], dD.x); acc2_bf16(acc2[1], dD.y); acc2_bf16(acc2[2], dD.z); acc2_bf16(acc2[3], dD.w);
    }
    for (; e < s1; e += 4) {
        int sA = es[e];
        uint4 dA = *(const uint4*)(x + (size_t)sA * 128 + cg * 8);
        acc2_bf16(acc2[0], dA.x); acc2_bf16(acc2[1], dA.y); acc2_bf16(acc2[2], dA.z); acc2_bf16(acc2[3], dA.w);
    }
    float acc[8];
    for (int i = 0; i < 4; ++i) { acc[2 * i] = acc2[i].x; acc[2 * i + 1] = acc2[i].y; }
    for (int off = 16; off < 64; off <<= 1)
        for (int i = 0; i < 8; ++i) acc[i] += __shfl_xor(acc[i], off);

    if (sub == 0) {
        float inv = inv_deg[node];
        v8us ov;
        for (int i = 0; i < 8; ++i) ov[i] = f2b(inv * acc[i]);
        *(v8us*)(ax + (size_t)node * 128 + cg * 8) = ov;
    }
}

// ---------------- Layer-1 dual-A GEMM: LDS-staged swizzled weights, single acc ----------
// Swizzle: 16B chunk c of row n stored at chunk index c^(n&15) -> 2-way bank alias only.
__global__ __launch_bounds__(256) void k_gemm2_g(
    const ushort_t* __restrict__ x,
    const ushort_t* __restrict__ ax,
    const ushort_t* __restrict__ Wts,
    const ushort_t* __restrict__ Wtn,
    const float* __restrict__ bias,
    ushort_t* out,
    int n) {
    __shared__ ushort_t ws[2 * 16384];   // 64 KB: [0]=Ws^T, [16384]=Wn^T
    int tid = threadIdx.x;
    int wave = tid >> 6, lane = tid & 63;
    int quad = lane >> 4, l16 = lane & 15;

    // stage 4096 16B chunks (coalesced reads, swizzled writes)
    for (int idx = tid; idx < 4096; idx += 256) {
        int m = idx >> 11;
        int rem = idx & 2047;
        int nrow = rem >> 4, c = rem & 15;
        const ushort_t* srcW = m ? Wtn : Wts;
        uint4 v = *(const uint4*)(srcW + nrow * 128 + c * 8);
        *(uint4*)(ws + m * 16384 + nrow * 128 + ((c ^ (nrow & 15)) * 8)) = v;
    }
    __syncthreads();

    int rowBase = blockIdx.x * 128 + wave * 32;
    v4f acc[2][8];
    for (int rt = 0; rt < 2; ++rt)
        for (int t = 0; t < 8; ++t)
            acc[rt][t] = (v4f){0.f, 0.f, 0.f, 0.f};

    for (int kk = 0; kk < 4; ++kk) {
        v8s a1[2], a2[2];
        for (int rt = 0; rt < 2; ++rt) {
            int row = rowBase + rt * 16 + l16;
            if (row >= n) row = n - 1;
            size_t off = (size_t)row * 128 + kk * 32 + quad * 8;
            a1[rt] = *(const v8s*)(x + off);
            a2[rt] = *(const v8s*)(ax + off);
        }
        int c = kk * 4 + quad;
        int cp8 = (c ^ l16) * 8;
        for (int t = 0; t < 8; ++t) {
            int nb = (t * 16 + l16) * 128 + cp8;
            const v8s bs = *(const v8s*)(ws + nb);
            const v8s bn = *(const v8s*)(ws + 16384 + nb);
            for (int rt = 0; rt < 2; ++rt) {
                acc[rt][t] = __builtin_amdgcn_mfma_f32_16x16x32_bf16(a1[rt], bs, acc[rt][t], 0, 0, 0);
                acc[rt][t] = __builtin_amdgcn_mfma_f32_16x16x32_bf16(a2[rt], bn, acc[rt][t], 0, 0, 0);
            }
        }
    }

    for (int rt = 0; rt < 2; ++rt)
        for (int t = 0; t < 8; ++t) {
            int col = t * 16 + l16;
            float bv = bias[col];
            for (int r = 0; r < 4; ++r) {
                int row = rowBase + rt * 16 + quad * 4 + r;
                if (row < n) {
                    float v = acc[rt][t][r] + bv;
                    v = fmaxf(v, 0.f);
                    out[(size_t)row * 128 + col] = f2b(v);
                }
            }
        }
}

// ---------------- Layer-2 GEMM fused with layer-3 split GEMM (64KB LDS union) ----------
// Stage Ws2/Wn2 swizzled (64KB) -> barrier -> phase-1 (B from LDS) -> barrier (weights dead)
// -> reuse LDS: x2 tile [0,17408) + staged Ws3/Wn3 [17408,29696) -> barrier -> phase-2 all-LDS.
__global__ __launch_bounds__(256) void k_gemm2s(
    const ushort_t* __restrict__ x,
    const ushort_t* __restrict__ ax,
    const ushort_t* __restrict__ Wts2,
    const ushort_t* __restrict__ Wtn2,
    const float* __restrict__ b2,
    const ushort_t* __restrict__ Wts3,
    const ushort_t* __restrict__ Wtn3,
    const float* __restrict__ b3,
    float* __restrict__ y3,
    ushort_t* __restrict__ h3,
    int n) {
    __shared__ ushort_t lds[32768];   // 64 KB union
    int tid = threadIdx.x;
    int wave = tid >> 6, lane = tid & 63;
    int quad = lane >> 4, l16 = lane & 15;
    int b = blockIdx.x;

    // stage phase-1 weights (swizzled)
    for (int idx = tid; idx < 4096; idx += 256) {
        int m = idx >> 11;
        int rem = idx & 2047;
        int nrow = rem >> 4, c = rem & 15;
        const ushort_t* srcW = m ? Wtn2 : Wts2;
        uint4 v = *(const uint4*)(srcW + nrow * 128 + c * 8);
        *(uint4*)(lds + m * 16384 + nrow * 128 + ((c ^ (nrow & 15)) * 8)) = v;
    }
    __syncthreads();

    // ---- Phase 1: layer-2 dual GEMM, B from LDS ----
    v4f acc[2][8];
    {
        int rowBase = b * 128 + wave * 32;
        for (int rt = 0; rt < 2; ++rt)
            for (int t = 0; t < 8; ++t)
                acc[rt][t] = (v4f){0.f, 0.f, 0.f, 0.f};
        for (int kk = 0; kk < 4; ++kk) {
            v8s a1[2], a2[2];
            for (int rt = 0; rt < 2; ++rt) {
                int row = rowBase + rt * 16 + l16;
                if (row >= n) row = n - 1;
                size_t off = (size_t)row * 128 + kk * 32 + quad * 8;
                a1[rt] = *(const v8s*)(x + off);
                a2[rt] = *(const v8s*)(ax + off);
            }
            int c = kk * 4 + quad;
            int cp8 = (c ^ l16) * 8;
            for (int t = 0; t < 8; ++t) {
                int nb = (t * 16 + l16) * 128 + cp8;
                const v8s bs = *(const v8s*)(lds + nb);
                const v8s bn = *(const v8s*)(lds + 16384 + nb);
                for (int rt = 0; rt < 2; ++rt) {
                    acc[rt][t] = __builtin_amdgcn_mfma_f32_16x16x32_bf16(a1[rt], bs, acc[rt][t], 0, 0, 0);
                    acc[rt][t] = __builtin_amdgcn_mfma_f32_16x16x32_bf16(a2[rt], bn, acc[rt][t], 0, 0, 0);
                }
            }
        }
    }
    __syncthreads();   // phase-1 weights dead; LDS region reusable

    // write x2 tile (rows 0..127, stride AXLD) into lds[0,17408)
    for (int rt = 0; rt < 2; ++rt)
        for (int t = 0; t < 8; ++t) {
            int col = t * 16 + l16;
            float bv = b2[col];
            for (int r = 0; r < 4; ++r) {
                int rowL = wave * 32 + rt * 16 + quad * 4 + r;
                float v = acc[rt][t][r] + bv;
                v = fmaxf(v, 0.f);
                lds[rowL * AXLD + col] = f2b(v);
            }
        }
    // stage phase-2 weights (48 rows x 128 each, swizzled) at 17408
    for (int idx = tid; idx < 1536; idx += 256) {
        int m = (idx >= 768) ? 1 : 0;
        int rem = idx - m * 768;
        int nrow = rem >> 4, c = rem & 15;
        const ushort_t* srcW = m ? Wtn3 : Wts3;
        uint4 v = *(const uint4*)(srcW + nrow * 128 + c * 8);
        *(uint4*)(lds + 17408 + m * 6144 + nrow * 128 + ((c ^ (nrow & 15)) * 8)) = v;
    }
    __syncthreads();

    // ---- Phase 2: layer-3 split GEMM, A and B from LDS ----
    {
        constexpr int H = 40;
        int rowBaseL = wave * 32;
        v4f accS[2][3], accN[2][3];
        for (int rt = 0; rt < 2; ++rt)
            for (int t = 0; t < 3; ++t) {
                accS[rt][t] = (v4f){0.f, 0.f, 0.f, 0.f};
                accN[rt][t] = (v4f){0.f, 0.f, 0.f, 0.f};
            }
        for (int kk = 0; kk < 4; ++kk) {
            v8s a1[2];
            for (int rt = 0; rt < 2; ++rt)
                a1[rt] = *(const v8s*)(&lds[(rowBaseL + rt * 16 + l16) * AXLD + kk * 32 + quad * 8]);
            int c = kk * 4 + quad;
            int cp8 = (c ^ l16) * 8;
            for (int t = 0; t < 3; ++t) {
                int nb = 17408 + (t * 16 + l16) * 128 + cp8;
                const v8s bs = *(const v8s*)(lds + nb);
                const v8s bn = *(const v8s*)(lds + 6144 + nb);
                for (int rt = 0; rt < 2; ++rt) {
                    accS[rt][t] = __builtin_amdgcn_mfma_f32_16x16x32_bf16(a1[rt], bs, accS[rt][t], 0, 0, 0);
                    accN[rt][t] = __builtin_amdgcn_mfma_f32_16x16x32_bf16(a1[rt], bn, accN[rt][t], 0, 0, 0);
                }
            }
        }
        for (int rt = 0; rt < 2; ++rt)
            for (int t = 0; t < 3; ++t) {
                int col = t * 16 + l16;
                if (col < H) {
                    float bv = b3[col];
                    for (int r = 0; r < 4; ++r) {
                        int row = b * 128 + rowBaseL + rt * 16 + quad * 4 + r;
                        if (row < n) {
                            size_t o = (size_t)row * H + col;
                            y3[o] = accS[rt][t][r] + bv;
                            h3[o] = f2b(accN[rt][t][r]);
                        }
                    }
                }
            }
    }
}

// ---------------- Layer-3 aggregation (H=40): 8 slots x 8 cols (5 active), f32 out ----------
__global__ __launch_bounds__(256) void k_agg3(
    const int* __restrict__ rs,
    const int* __restrict__ es,
    const float* __restrict__ inv_deg,
    const ushort_t* __restrict__ h3,
    const float* __restrict__ y3,
    float* __restrict__ out,
    int n) {
    int tid = threadIdx.x;
    int wave = tid >> 6, lane = tid & 63;
    int node = blockIdx.x * 4 + wave;
    if (node >= n) return;
    int sub = lane >> 3;
    int cg = lane & 7;
    bool act = (cg < 5);

    int s0 = rs[node], s1 = rs[node + 1];
    v2f acc2[4];
    for (int i = 0; i < 4; ++i) acc2[i] = (v2f){0.f, 0.f};

    if (act) {
        int e = s0 + sub;
        for (; e + 8 < s1; e += 16) {
            int sA = es[e], sB = es[e + 8];
            uint4 dA = *(const uint4*)(h3 + (size_t)sA * 40 + cg * 8);
            uint4 dB = *(const uint4*)(h3 + (size_t)sB * 40 + cg * 8);
            acc2_bf16(acc2[0], dA.x); acc2_bf16(acc2[1], dA.y); acc2_bf16(acc2[2], dA.z); acc2_bf16(acc2[3], dA.w);
            acc2_bf16(acc2[0], dB.x); acc2_bf16(acc2[1], dB.y); acc2_bf16(acc2[2], dB.z); acc2_bf16(acc2[3], dB.w);
        }
        if (e < s1) {
            int sA = es[e];
            uint4 dA = *(const uint4*)(h3 + (size_t)sA * 40 + cg * 8);
            acc2_bf16(acc2[0], dA.x); acc2_bf16(acc2[1], dA.y); acc2_bf16(acc2[2], dA.z); acc2_bf16(acc2[3], dA.w);
        }
    }
    float acc[8];
    for (int i = 0; i < 4; ++i) { acc[2 * i] = acc2[i].x; acc[2 * i + 1] = acc2[i].y; }
    for (int off = 8; off < 64; off <<= 1)
        for (int i = 0; i < 8; ++i) acc[i] += __shfl_xor(acc[i], off);

    if (sub == 0 && act) {
        float inv = inv_deg[node];
        const float4* yp = (const float4*)(y3 + (size_t)node * 40 + cg * 8);
        float4 y0 = yp[0], y1 = yp[1];
        size_t base = (size_t)node * 40 + cg * 8;
        float4* op = (float4*)(out + base);
        op[0] = (float4){y0.x + inv * acc[0], y0.y + inv * acc[1],
                         y0.z + inv * acc[2], y0.w + inv * acc[3]};
        op[1] = (float4){y1.x + inv * acc[4], y1.y + inv * acc[5],
                         y1.z + inv * acc[6], y1.w + inv * acc[7]};
    }
}

__global__ void k_zero16(ushort_t* p, int n) {
    int i = blockIdx.x * 256 + threadIdx.x;
    if (i < n) p[i] = 0;
}

// ---------------- launch ----------------

extern "C" void kernel_launch(void* const* d_in, const int* in_sizes, int n_in,
                              void* d_out, int out_size, void* d_ws, size_t ws_size,
                              hipStream_t stream) {
    const int* src = (const int*)d_in[1];
    const int* dst = (const int*)d_in[2];

    const int N = N_NODES, E = N_EDGES;

    char* ws = (char*)d_ws;
    size_t o = 0;
    auto alloc = [&](size_t bytes) {
        char* p = ws + o;
        o = (o + bytes + 511) & ~(size_t)511;
        return p;
    };
    float* inv_deg = (float*)alloc(N * 4);
    int* rs        = (int*)alloc((N + 1) * 4);
    int* bcnt      = (int*)alloc(NBUCK * 4);
    int* boff      = (int*)alloc(NBUCK * 4);
    int* bcur      = (int*)alloc(NBUCK * 4);
    int* es        = (int*)alloc((size_t)E * 4);
    ushort_t* xbuf = (ushort_t*)alloc((size_t)N * 128 * 2);
    char* aggX_raw = (char*)alloc((size_t)N * 128 * 2);   // 25.6 MB: packed, then aggX
    ushort_t* aggX = (ushort_t*)aggX_raw;
    uint* packed   = (uint*)aggX_raw;                      // pre-CSR only
    char* conv_raw = (char*)alloc((size_t)N * 128 * 2);   // 25.6 MB: conv0, then h3+y3
    ushort_t* conv0 = (ushort_t*)conv_raw;
    ushort_t* h3   = (ushort_t*)conv_raw;                  // 8 MB (layer 3)
    float* y3      = (float*)(conv_raw + (size_t)N * 40 * 2 + 512);  // 16 MB after h3
    ushort_t* Wt[6];
    Wt[0] = (ushort_t*)alloc(128 * 128 * 2);
    Wt[1] = (ushort_t*)alloc(128 * 128 * 2);
    Wt[2] = (ushort_t*)alloc(128 * 128 * 2);
    Wt[3] = (ushort_t*)alloc(128 * 128 * 2);
    Wt[4] = (ushort_t*)alloc(48 * 128 * 2);
    Wt[5] = (ushort_t*)alloc(48 * 128 * 2);
    size_t need = o;

    if (ws_size < need) {
        k_zero16<<<(out_size + 255) / 256, 256, 0, stream>>>((ushort_t*)d_out, out_size);
        return;
    }

    int nb_agg = (N + 3) / 4;        // 25000

    const float* b1 = (const float*)d_in[5];
    const float* b2 = (const float*)d_in[8];
    const float* b3 = (const float*)d_in[11];

    // prep: zero bcnt, then weights+feat+hist in one kernel
    hipMemsetAsync(bcnt, 0, NBUCK * 4, stream);
    WConvArgs wa;
    wa.srcW[0] = (const float*)d_in[3]; wa.srcW[1] = (const float*)d_in[4];
    wa.srcW[2] = (const float*)d_in[6]; wa.srcW[3] = (const float*)d_in[7];
    wa.srcW[4] = (const float*)d_in[9]; wa.srcW[5] = (const float*)d_in[10];
    for (int i = 0; i < 6; ++i) wa.dstW[i] = Wt[i];
    k_prep<<<NB_W + NB_CONV + NTILE, 256, 0, stream>>>(wa, (const float4*)d_in[0], conv0, dst, bcnt);

    // CSR via bucket sort
    k_bscan<<<1, 1024, 0, stream>>>(bcnt, boff, bcur);
    k_bscatter<<<NTILE, 256, 0, stream>>>(src, dst, bcur, packed);
    k_binsort<<<NBUCK, 256, 0, stream>>>(packed, bcnt, boff, rs, inv_deg, es);

    // Layer 1: aggregate conv0 -> aggX; GEMM -> xbuf
    k_agg<<<nb_agg, 256, 0, stream>>>(rs, es, inv_deg, conv0, aggX, N);
    k_gemm2_g<<<NBUCK, 256, 0, stream>>>(conv0, aggX, Wt[0], Wt[1], b1, xbuf, N);
    // Layer 2: aggregate xbuf -> aggX; fused layer-2 GEMM + layer-3 split GEMM -> y3,h3
    k_agg<<<nb_agg, 256, 0, stream>>>(rs, es, inv_deg, xbuf, aggX, N);
    k_gemm2s<<<NBUCK, 256, 0, stream>>>(xbuf, aggX, Wt[2], Wt[3], b2, Wt[4], Wt[5], b3, y3, h3, N);
    // Layer 3 aggregation -> d_out (f32)
    k_agg3<<<nb_agg, 256, 0, stream>>>(rs, es, inv_deg, h3, y3, (float*)d_out, N);
}